// Round 13
// baseline (394.686 us; speedup 1.0000x reference)
//
#include <hip/hip_runtime.h>

#define NB 8192
#define NT 512

typedef unsigned int u32;
typedef unsigned short u16;
typedef float f32x2 __attribute__((ext_vector_type(2)));
typedef float f32x4 __attribute__((ext_vector_type(4)));
typedef u32 u32x3 __attribute__((ext_vector_type(3)));
typedef _Float16 h16x2 __attribute__((ext_vector_type(2)));

__device__ __forceinline__ float rcp_(float x){ return __builtin_amdgcn_rcpf(x); }
__device__ __forceinline__ float exp2_(float x){ return __builtin_amdgcn_exp2f(x); }
__device__ __forceinline__ float tanh_(float x){ return 1.0f - 2.0f*rcp_(1.0f + exp2_(2.88539008177792681f*x)); }

#define PINF(v)  asm volatile("" : "+v"(v))

#define QP_XOR2 0x4E
#define QP_ROT1 0x39
#define QP_ROT3 0x93
#define QP_BC0  0x00
#define QP_BC1  0x55
#define QP_BC3  0xFF
template<int C>
__device__ __forceinline__ float dppf(float x){
    return __int_as_float(__builtin_amdgcn_update_dpp(0, __float_as_int(x), C, 0xF, 0xF, true));
}
// lane^4 exchange, pure VALU (validated R10/R11/R12)
__device__ __forceinline__ float swz4(float x){
    int v = __builtin_amdgcn_update_dpp(__float_as_int(x), __float_as_int(x), 0x104, 0xF, 0x5, false);
    v     = __builtin_amdgcn_update_dpp(v,                 __float_as_int(x), 0x114, 0xF, 0xA, false);
    return __int_as_float(v);
}
__device__ __forceinline__ u32 swz4u(u32 x){
    int v = __builtin_amdgcn_update_dpp((int)x, (int)x, 0x104, 0xF, 0x5, false);
    v     = __builtin_amdgcn_update_dpp(v,      (int)x, 0x114, 0xF, 0xA, false);
    return (u32)v;
}

__device__ __forceinline__ float upkh(u16 v){ _Float16 h; __builtin_memcpy(&h,&v,2); return (float)h; }
__device__ __forceinline__ float upk_lo(u32 v){ return upkh((u16)(v&0xffffu)); }
__device__ __forceinline__ float upk_hi(u32 v){ return upkh((u16)(v>>16)); }
__device__ __forceinline__ u32 pkrtz(float a, float b){
    auto p = __builtin_amdgcn_cvt_pkrtz(a, b);
    return __builtin_bit_cast(u32, p);
}

__device__ __forceinline__ float dot2f(h16x2 a, h16x2 b, float c){
#if __has_builtin(__builtin_amdgcn_fdot2)
    return __builtin_amdgcn_fdot2(a, b, c, false);
#else
    return fmaf((float)a.x, (float)b.x, fmaf((float)a.y, (float)b.y, c));
#endif
}
__device__ __forceinline__ float dot2u(u32 w, u32 d, float c){
    return dot2f(__builtin_bit_cast(h16x2, w), __builtin_bit_cast(h16x2, d), c);
}

#define SEL_LL 0x05040100u
#define SEL_HL 0x05040302u
#define SEL_HH 0x07060302u

// ---------------------------------------------------------------------------
// 8-lane-per-seq: q=lane&7; gate g=q&3 (0=i,1=f,2=g,3=o); half m=q>>2.
// ---------------------------------------------------------------------------
__device__ __forceinline__ void cell_update(const float a[3], float c[3], float ho[3], int g){
    float ov[3];
#pragma unroll
    for (int i=0;i<3;++i){
        const float t   = dppf<QP_XOR2>(a[i]);
        const float u   = a[i]*t;
        const float ig  = dppf<QP_BC0>(u);
        const float fc  = a[i]*c[i];
        const float fcb = dppf<QP_BC1>(fc);
        c[i]  = ig + fcb;
        ov[i] = dppf<QP_BC3>(a[i]);
    }
    const float cg = (g==1) ? c[1] : ((g==2) ? c[2] : c[0]);
    const float tg = tanh_(cg);
    const float w1 = dppf<QP_ROT1>(tg);
    const float w2 = dppf<QP_XOR2>(tg);
    const float w3 = dppf<QP_ROT3>(tg);
#pragma unroll
    for (int j=0;j<3;++j){
        const int r = (j - g) & 3;
        const float lo = (r & 1) ? w1 : tg;
        const float hi = (r & 1) ? w3 : w2;
        ho[j] = ov[j] * ((r & 2) ? hi : lo);
    }
}

// pA=(h3m,h3m+1), pB=(h3m+2,·), pr1=(h3m+2, hx0), pr2=(hx1,hx2)
__device__ __forceinline__ void packh(const float ho[3], u32& pA, u32& pB, u32& pr1, u32& pr2){
    pA = pkrtz(ho[0], ho[1]);
    pB = pkrtz(ho[2], ho[2]);
    const u32 qA = swz4u(pA);
    const u32 qB = swz4u(pB);
    pr1 = __builtin_amdgcn_perm(qA, pB, SEL_LL);
    pr2 = __builtin_amdgcn_perm(qB, qA, SEL_HL);
}

// ---------------------------------------------------------------------------
// K1: layer-0 BACKWARD direction only. 1024 waves. Pair-packed dwordx3 store
// (layout identical to R11/R12 bwd region): per group (2 steps), per seq:
// m=0 triple at +0, m=1 at +12; d0=(h0,h1)E, d1=(h2E,h0O), d2=(h1O,h2O).
// ---------------------------------------------------------------------------
__global__ __launch_bounds__(64)
__attribute__((amdgpu_waves_per_eu(1,1)))
void lstm_l0b(
    const float* __restrict__ x,
    const float* __restrict__ h0, const float* __restrict__ c0,
    const float* __restrict__ Wb, const float* __restrict__ Ub, const float* __restrict__ bb,
    char* __restrict__ bbuf)
{
    const int tid = blockIdx.x*64 + threadIdx.x;
    const int q   = tid & 7;
    const int b   = tid >> 3;
    const int g   = q & 3;
    const int m   = q >> 2;

    const float cE = (g==2) ? -2.88539008177792681f : -1.44269504088896341f;
    const float cM = (g==2) ? 2.0f : 1.0f;
    const float cB = (g==2) ? -1.0f : 0.0f;

    u32 whx[3][3], whu[3][3];
    float cEb[3];
#pragma unroll
    for (int i=0;i<3;++i){
        const int r = g*6 + 3*m + i;
#pragma unroll
        for (int k=0;k<3;++k) whx[i][k] = pkrtz(cE*Wb[r*6+2*k], cE*Wb[r*6+2*k+1]);
        whu[i][0] = pkrtz(cE*Ub[r*6+3*m+0],     cE*Ub[r*6+3*m+1]);
        whu[i][1] = pkrtz(cE*Ub[r*6+3*m+2],     cE*Ub[r*6+3*(1-m)+0]);
        whu[i][2] = pkrtz(cE*Ub[r*6+3*(1-m)+1], cE*Ub[r*6+3*(1-m)+2]);
        cEb[i] = cE * bb[r];
    }
#pragma unroll
    for (int i=0;i<3;++i){
#pragma unroll
        for (int k=0;k<3;++k){ PINF(whx[i][k]); PINF(whu[i][k]); }
        PINF(cEb[i]);
    }

    float cc[3];
    u32 pA, pB, pr1, pr2;
    {
        const int base = 1*(NB*6) + b*6;
        float ho[3];
#pragma unroll
        for (int i=0;i<3;++i){
            ho[i] = h0[base+3*m+i];
            cc[i] = c0[base+3*m+i];
        }
        packh(ho, pA, pB, pr1, pr2);
    }

    const float* xb = x + (size_t)b*(NT*6);
    const size_t tstr2 = (size_t)NB*24;
    char* op = bbuf + (size_t)b*24 + m*12 + (size_t)(NT/2-1)*tstr2;

    f32x4 xA[3], xB[3];
    auto ldg = [&](int grp, f32x4* d){
        const int tlo = NT-2 - 2*grp;
        const f32x4* p = (const f32x4*)(xb + (size_t)tlo*6);
        d[0]=p[0]; d[1]=p[1]; d[2]=p[2];
    };

    auto STEP = [&](u32 px0, u32 px1, u32 px2){
        float a[3];
#pragma unroll
        for (int i=0;i<3;++i){
            float s = dot2u(whu[i][2], pr2, cEb[i]);
            s = dot2u(whu[i][1], pr1, s);
            s = dot2u(whu[i][0], pA,  s);
            s = dot2u(whx[i][2], px2, s);
            s = dot2u(whx[i][1], px1, s);
            s = dot2u(whx[i][0], px0, s);
            a[i] = fmaf(cM, rcp_(1.0f + exp2_(s)), cB);
        }
        float ho[3];
        cell_update(a, cc, ho, g);
        packh(ho, pA, pB, pr1, pr2);
    };

    auto GROUP = [&](const f32x4* d){
        // odd step first (t = tlo+1): floats 6-11
        STEP(pkrtz(d[1].z,d[1].w), pkrtz(d[2].x,d[2].y), pkrtz(d[2].z,d[2].w));
        const u32 s10 = pA, s11 = pB;
        // even step (t = tlo): floats 0-5
        STEP(pkrtz(d[0].x,d[0].y), pkrtz(d[0].z,d[0].w), pkrtz(d[1].x,d[1].y));
        if (g == 0){
            u32x3 v;
            v.x = pA;
            v.y = __builtin_amdgcn_perm(s10, pB, SEL_LL);  // (h2E, h0O)
            v.z = __builtin_amdgcn_perm(s11, s10, SEL_HL); // (h1O, h2O)
            *(u32x3*)op = v;
        }
        op -= tstr2;
    };

    ldg(0, xA); ldg(1, xB);
    for (int gi=0; gi<NT/2; gi+=2){
        GROUP(xA);
        { int gp = gi+2; if (gp > NT/2-1) gp = NT/2-1; ldg(gp, xA); }
        GROUP(xB);
        { int gp = gi+3; if (gp > NT/2-1) gp = NT/2-1; ldg(gp, xB); }
    }
}

// ---------------------------------------------------------------------------
// K2: fused forward pass — f0 recomputed in registers, feeding f1 directly;
// r0 streamed from bbuf; + r1 single step + FC head. 1024 waves.
// Two independent ~450cy recurrence chains per wave (f0[t+1] || f1[t]).
// Zero stores in the main loop.
// ---------------------------------------------------------------------------
__global__ __launch_bounds__(64)
__attribute__((amdgpu_waves_per_eu(1,1)))
void lstm_fused(
    const char* __restrict__ bbuf,
    const float* __restrict__ x,
    const float* __restrict__ h0, const float* __restrict__ c0,
    const float* __restrict__ W0f, const float* __restrict__ U0f, const float* __restrict__ b0f,
    const float* __restrict__ W1f, const float* __restrict__ U1f, const float* __restrict__ b1f,
    const float* __restrict__ W1b, const float* __restrict__ U1b, const float* __restrict__ b1b,
    const float* __restrict__ fcw, const float* __restrict__ fcb,
    float* __restrict__ out)
{
    const int tid = blockIdx.x*64 + threadIdx.x;
    const int q = tid & 7;
    const int b = tid >> 3;
    const int g = q & 3;
    const int m = q >> 2;

    const float cE = (g==2) ? -2.88539008177792681f : -1.44269504088896341f;
    const float cM = (g==2) ? 2.0f : 1.0f;
    const float cB = (g==2) ? -1.0f : 0.0f;

    // ---- f0 weights (input dim 6) ----
    u32 whx0[3][3], whu0[3][3];
    float cEb0[3];
    // ---- f1 weights (input = [f0(6) from packh regs | r0(6) from buffer]) ----
    u32 wf1[3][3], wr1[3][3], whu1[3][3];
    float cEb1[3];
#pragma unroll
    for (int i=0;i<3;++i){
        const int r = g*6 + 3*m + i;
#pragma unroll
        for (int k=0;k<3;++k) whx0[i][k] = pkrtz(cE*W0f[r*6+2*k], cE*W0f[r*6+2*k+1]);
        whu0[i][0] = pkrtz(cE*U0f[r*6+3*m+0],     cE*U0f[r*6+3*m+1]);
        whu0[i][1] = pkrtz(cE*U0f[r*6+3*m+2],     cE*U0f[r*6+3*(1-m)+0]);
        whu0[i][2] = pkrtz(cE*U0f[r*6+3*(1-m)+1], cE*U0f[r*6+3*(1-m)+2]);
        cEb0[i] = cE * b0f[r];

        const float* Wr = W1f + r*12;
        // f0-part pairs matching packh register order (pA, pr1, pr2):
        wf1[i][0] = pkrtz(cE*Wr[3*m+0],     cE*Wr[3*m+1]);
        wf1[i][1] = pkrtz(cE*Wr[3*m+2],     cE*Wr[3*(1-m)+0]);
        wf1[i][2] = pkrtz(cE*Wr[3*(1-m)+1], cE*Wr[3*(1-m)+2]);
        // r0-part pairs matching buffer dwords: (c6,c7)(c9,c10)(c8,c11)
        wr1[i][0] = pkrtz(cE*Wr[6], cE*Wr[7]);
        wr1[i][1] = pkrtz(cE*Wr[9], cE*Wr[10]);
        wr1[i][2] = pkrtz(cE*Wr[8], cE*Wr[11]);
        whu1[i][0] = pkrtz(cE*U1f[r*6+3*m+0],     cE*U1f[r*6+3*m+1]);
        whu1[i][1] = pkrtz(cE*U1f[r*6+3*m+2],     cE*U1f[r*6+3*(1-m)+0]);
        whu1[i][2] = pkrtz(cE*U1f[r*6+3*(1-m)+1], cE*U1f[r*6+3*(1-m)+2]);
        cEb1[i] = cE * b1f[r];
    }
#pragma unroll
    for (int i=0;i<3;++i){
#pragma unroll
        for (int k=0;k<3;++k){
            PINF(whx0[i][k]); PINF(whu0[i][k]);
            PINF(wf1[i][k]);  PINF(wr1[i][k]); PINF(whu1[i][k]);
        }
        PINF(cEb0[i]); PINF(cEb1[i]);
    }

    float cc0[3], cc1[3], ho0[3], ho1[3];
    u32 p0A, p0B, p0r1, p0r2;
    u32 p1A, p1B, p1r1, p1r2;
    {
        const int base0 = 0*(NB*6) + b*6;
        const int base1 = 2*(NB*6) + b*6;
#pragma unroll
        for (int i=0;i<3;++i){
            ho0[i] = h0[base0+3*m+i];  cc0[i] = c0[base0+3*m+i];
            ho1[i] = h0[base1+3*m+i];  cc1[i] = c0[base1+3*m+i];
        }
        packh(ho0, p0A, p0B, p0r1, p0r2);
        packh(ho1, p1A, p1B, p1r1, p1r2);
    }

    const float* xb = x + (size_t)b*(NT*6);
    const char* pbB = bbuf + (size_t)b*24;
    const size_t tstr2 = (size_t)NB*24;

    f32x4 xA[3], xB[3];
    u32 BA[6], BB[6];
    auto ldg = [&](int grp, f32x4* d){
        const f32x4* p = (const f32x4*)(xb + (size_t)(2*grp)*6);
        d[0]=p[0]; d[1]=p[1]; d[2]=p[2];
    };
    auto loadB = [&](int grp, u32* Bv){
        const char* bp_ = pbB + (size_t)grp*tstr2;
        u32x3 c0v = *(const u32x3*)(bp_);
        u32x3 c1v = *(const u32x3*)(bp_+12);
        Bv[0]=c0v.x; Bv[1]=c0v.y; Bv[2]=c0v.z; Bv[3]=c1v.x; Bv[4]=c1v.y; Bv[5]=c1v.z;
    };

    auto STEP0 = [&](u32 px0, u32 px1, u32 px2){
        float a[3];
#pragma unroll
        for (int i=0;i<3;++i){
            float s = dot2u(whu0[i][2], p0r2, cEb0[i]);
            s = dot2u(whu0[i][1], p0r1, s);
            s = dot2u(whu0[i][0], p0A,  s);
            s = dot2u(whx0[i][2], px2, s);
            s = dot2u(whx0[i][1], px1, s);
            s = dot2u(whx0[i][0], px0, s);
            a[i] = fmaf(cM, rcp_(1.0f + exp2_(s)), cB);
        }
        cell_update(a, cc0, ho0, g);
        packh(ho0, p0A, p0B, p0r1, p0r2);
    };
    auto STEP1 = [&](u32 d3, u32 d4, u32 d5){
        float a[3];
#pragma unroll
        for (int i=0;i<3;++i){
            float s = dot2u(whu1[i][2], p1r2, cEb1[i]);
            s = dot2u(whu1[i][1], p1r1, s);
            s = dot2u(whu1[i][0], p1A,  s);
            s = dot2u(wf1[i][0], p0A,  s);
            s = dot2u(wf1[i][1], p0r1, s);
            s = dot2u(wf1[i][2], p0r2, s);
            s = dot2u(wr1[i][0], d3, s);
            s = dot2u(wr1[i][1], d4, s);
            s = dot2u(wr1[i][2], d5, s);
            a[i] = fmaf(cM, rcp_(1.0f + exp2_(s)), cB);
        }
        cell_update(a, cc1, ho1, g);
        packh(ho1, p1A, p1B, p1r1, p1r2);
    };

    auto GROUP = [&](const f32x4* d, const u32* Bv){
        // even step
        STEP0(pkrtz(d[0].x,d[0].y), pkrtz(d[0].z,d[0].w), pkrtz(d[1].x,d[1].y));
        STEP1(Bv[0], Bv[3], __builtin_amdgcn_perm(Bv[4], Bv[1], SEL_LL));
        // odd step
        STEP0(pkrtz(d[1].z,d[1].w), pkrtz(d[2].x,d[2].y), pkrtz(d[2].z,d[2].w));
        STEP1(__builtin_amdgcn_perm(Bv[2], Bv[1], SEL_HL),
              __builtin_amdgcn_perm(Bv[5], Bv[4], SEL_HL),
              __builtin_amdgcn_perm(Bv[5], Bv[2], SEL_HH));
    };

    ldg(0, xA); loadB(0, BA);
    ldg(1, xB); loadB(1, BB);
    for (int gi=0; gi<NT/2; gi+=2){
        GROUP(xA, BA);
        { int gp = gi+2; if (gp > NT/2-1) gp = NT/2-1; ldg(gp, xA); loadB(gp, BA); }
        GROUP(xB, BB);
        { int gp = gi+3; if (gp > NT/2-1) gp = NT/2-1; ldg(gp, xB); loadB(gp, BB); }
    }
    // ho0 = f0[511] (f32), ho1 = f1[511] (f32); BB holds r0 group 255.

    float hx1[3];
#pragma unroll
    for (int i=0;i<3;++i) hx1[i] = swz4(ho1[i]);

    // l0[511] as f32: own half from ho0, other half via swz4, r0 from BB odd-step
    float in[12];
#pragma unroll
    for (int i=0;i<3;++i){
        in[3*m+i]     = ho0[i];
        in[3*(1-m)+i] = swz4(ho0[i]);
    }
    in[6]=upk_hi(BB[1]); in[7]=upk_lo(BB[2]); in[8]=upk_hi(BB[2]);
    in[9]=upk_hi(BB[4]); in[10]=upk_lo(BB[5]); in[11]=upk_hi(BB[5]);

    // ---- r1: single reverse-direction step at t = NT-1 (f32 math) ----
    const int base3 = 3*(NB*6) + b*6;
    float hr[6];
#pragma unroll
    for (int j=0;j<6;++j) hr[j] = h0[base3 + j];
    float cr[3];
#pragma unroll
    for (int i=0;i<3;++i) cr[i] = c0[base3 + 3*m + i];

    float a[3];
#pragma unroll
    for (int i=0;i<3;++i){
        const int r = g*6 + 3*m + i;
        float acc = b1b[r];
#pragma unroll
        for (int k=0;k<12;++k) acc = fmaf(W1b[r*12+k], in[k], acc);
#pragma unroll
        for (int j=0;j<6;++j)  acc = fmaf(U1b[r*6+j], hr[j], acc);
        a[i] = fmaf(cM, rcp_(1.0f + exp2_(cE*acc)), cB);
    }
    float r1o[3];
    cell_update(a, cr, r1o, g);
    float r1x[3];
#pragma unroll
    for (int i=0;i<3;++i) r1x[i] = swz4(r1o[i]);

    // ---- head ----
    if (g == 0){
#pragma unroll
        for (int i=0;i<3;++i){
            const int r = 3*m + i;
            float acc = fcb[r];
#pragma unroll
            for (int k=0;k<3;++k){
                acc = fmaf(fcw[r*12 + 3*m + k],         fmaxf(ho1[k],0.f), acc);
                acc = fmaf(fcw[r*12 + 3*(1-m) + k],     fmaxf(hx1[k],0.f), acc);
                acc = fmaf(fcw[r*12 + 6 + 3*m + k],     fmaxf(r1o[k],0.f), acc);
                acc = fmaf(fcw[r*12 + 6 + 3*(1-m) + k], fmaxf(r1x[k],0.f), acc);
            }
            out[b*6 + r] = acc;
        }
    }
}

extern "C" void kernel_launch(void* const* d_in, const int* in_sizes, int n_in,
                              void* d_out, int out_size, void* d_ws, size_t ws_size,
                              hipStream_t stream)
{
    (void)in_sizes; (void)n_in; (void)out_size; (void)ws_size;
    const float* x    = (const float*)d_in[0];
    const float* h0   = (const float*)d_in[1];
    const float* c0   = (const float*)d_in[2];
    const float* W0f  = (const float*)d_in[3];
    const float* U0f  = (const float*)d_in[4];
    const float* b0f  = (const float*)d_in[5];
    const float* W0b  = (const float*)d_in[6];
    const float* U0b  = (const float*)d_in[7];
    const float* b0b  = (const float*)d_in[8];
    const float* W1f  = (const float*)d_in[9];
    const float* U1f  = (const float*)d_in[10];
    const float* b1f  = (const float*)d_in[11];
    const float* W1b  = (const float*)d_in[12];
    const float* U1b  = (const float*)d_in[13];
    const float* b1b  = (const float*)d_in[14];
    const float* fcw  = (const float*)d_in[15];
    const float* fcb  = (const float*)d_in[16];
    float* out = (float*)d_out;
    char* ws = (char*)d_ws;

    char* bbuf = ws;   // (NT/2)*NB*24 = 50.3 MB

    lstm_l0b<<<dim3(1024), dim3(64), 0, stream>>>(x, h0, c0, W0b, U0b, b0b, bbuf);
    lstm_fused<<<dim3(1024), dim3(64), 0, stream>>>(bbuf, x, h0, c0,
        W0f, U0f, b0f, W1f, U1f, b1f, W1b, U1b, b1b, fcw, fcb, out);
}

// Round 17
// 276.524 us; speedup vs baseline: 1.4273x; 1.4273x over previous
//
#include <hip/hip_runtime.h>

#define NB 8192
#define NT 512

typedef unsigned int u32;
typedef unsigned short u16;
typedef float f32x4 __attribute__((ext_vector_type(4)));
typedef u32 u32x2 __attribute__((ext_vector_type(2)));
typedef _Float16 h16x2 __attribute__((ext_vector_type(2)));

__device__ __forceinline__ float rcp_(float x){ return __builtin_amdgcn_rcpf(x); }
__device__ __forceinline__ float exp2_(float x){ return __builtin_amdgcn_exp2f(x); }
// tanh(x) = 1 - 2/(1+exp2(2x*log2e)); saturates correctly at +/-inf.
__device__ __forceinline__ float tanh_(float x){ return 1.0f - 2.0f*rcp_(1.0f + exp2_(2.88539008177792681f*x)); }
__device__ __forceinline__ float sigm(float x){ return rcp_(1.0f + exp2_(-1.44269504088896341f*x)); }

#define PINF(v)  asm volatile("" : "+v"(v))

// Broadcast lane (group8_base + J) to all 8 lanes of the group.
// ds_swizzle BitMode: offset = (xor<<10)|(or<<5)|and ; src = ((l & and)|or)^xor.
// and=0x18 keeps the 8-group base (bits 3,4 of the 32-half), or=J selects lane J.
// Encoding family validated on-HW by the 0x101F xor-4 swizzle (R4/R5).
template<int J>
__device__ __forceinline__ float swzbc(float x){
    return __int_as_float(__builtin_amdgcn_ds_swizzle(__float_as_int(x), (J<<5)|0x18));
}

__device__ __forceinline__ float upkh(u16 v){ _Float16 h; __builtin_memcpy(&h,&v,2); return (float)h; }
__device__ __forceinline__ float upk_lo(u32 v){ return upkh((u16)(v&0xffffu)); }
__device__ __forceinline__ float upk_hi(u32 v){ return upkh((u16)(v>>16)); }
__device__ __forceinline__ u32 pkrtz(float a, float b){
    auto p = __builtin_amdgcn_cvt_pkrtz(a, b);
    return __builtin_bit_cast(u32, p);
}
__device__ __forceinline__ float dot2f(h16x2 a, h16x2 b, float c){
#if __has_builtin(__builtin_amdgcn_fdot2)
    return __builtin_amdgcn_fdot2(a, b, c, false);
#else
    return fmaf((float)a.x, (float)b.x, fmaf((float)a.y, (float)b.y, c));
#endif
}
__device__ __forceinline__ float dot2u(u32 w, u32 d, float c){
    return dot2f(__builtin_bit_cast(h16x2, w), __builtin_bit_cast(h16x2, d), c);
}

// ---------------------------------------------------------------------------
// Lane layout: 8 lanes per sequence; lane j (j<6) owns hidden unit j and
// computes ALL FOUR GATES of it locally (rows g*6+j, g=0..3). Cell update is
// lane-local (no DPP web, no selects). Cross-lane per step = 6 swizzle
// broadcasts of h + 3 pkrtz; the resulting dwords (h01,h23,h45) feed the next
// step's dense AND are the store triple.
// Gate prescale folded into weights: sigmoid rows cs=-log2e, tanh(g) row
// cs=-2log2e; z comes out pre-scaled for exp2.
// Buffer layout per (t-pair, seq): 24B = 6 dwords
//   [h01@E, h01@O, h23@E, h23@O, h45@E, h45@O]   (fp16 pairs, E=even t, O=odd)
// ---------------------------------------------------------------------------

// Layer 0, both directions. 2048 blocks x 64 = 2048 waves (2/SIMD).
__global__ __launch_bounds__(64)
__attribute__((amdgpu_waves_per_eu(2,2)))
void lstm_l0v2(
    const float* __restrict__ x,
    const float* __restrict__ h0, const float* __restrict__ c0,
    const float* __restrict__ Wf, const float* __restrict__ Uf, const float* __restrict__ bf,
    const float* __restrict__ Wb, const float* __restrict__ Ub, const float* __restrict__ bbv,
    char* __restrict__ fbuf, char* __restrict__ bbuf)
{
    const int l  = threadIdx.x;
    const int j  = l & 7;
    const int jj = (j < 6) ? j : (j - 2);       // lanes 6,7 duplicate hidden 4,5 (results unused)
    const int e  = blockIdx.x*8 + (l >> 3);
    const int b  = e & (NB-1);
    const int dir = e >> 13;

    const float* W  = dir ? Wb  : Wf;
    const float* U  = dir ? Ub  : Uf;
    const float* bi = dir ? bbv : bf;

    u32 wd[4][6]; float cEb[4];
#pragma unroll
    for (int g=0; g<4; ++g){
        const int row = g*6 + jj;
        const float cs = (g==2) ? -2.88539008177792681f : -1.44269504088896341f;
#pragma unroll
        for (int k=0;k<3;++k) wd[g][k]   = pkrtz(cs*W[row*6+2*k], cs*W[row*6+2*k+1]);
#pragma unroll
        for (int k=0;k<3;++k) wd[g][3+k] = pkrtz(cs*U[row*6+2*k], cs*U[row*6+2*k+1]);
        cEb[g] = cs * bi[row];
    }
#pragma unroll
    for (int g=0; g<4; ++g){
#pragma unroll
        for (int k=0;k<6;++k) PINF(wd[g][k]);
        PINF(cEb[g]);
    }

    float cc = c0[dir*(NB*6) + b*6 + jj];
    float hn = h0[dir*(NB*6) + b*6 + jj];
    u32 d01, d23, d45;
    {
        const float t0=swzbc<0>(hn), t1=swzbc<1>(hn), t2=swzbc<2>(hn),
                    t3=swzbc<3>(hn), t4=swzbc<4>(hn), t5=swzbc<5>(hn);
        d01=pkrtz(t0,t1); d23=pkrtz(t2,t3); d45=pkrtz(t4,t5);
    }

    const char* xb = (const char*)(x + (size_t)b*(NT*6));
    char* obase = (dir ? bbuf : fbuf) + (size_t)b*24 + j*8;   // used when j<3
    const size_t tstr = (size_t)NB*24;

    auto STEP = [&](u32 px0, u32 px1, u32 px2){
        float z0=cEb[0], z1=cEb[1], z2=cEb[2], z3=cEb[3];
        z0=dot2u(wd[0][0],px0,z0); z0=dot2u(wd[0][1],px1,z0); z0=dot2u(wd[0][2],px2,z0);
        z0=dot2u(wd[0][3],d01,z0); z0=dot2u(wd[0][4],d23,z0); z0=dot2u(wd[0][5],d45,z0);
        z1=dot2u(wd[1][0],px0,z1); z1=dot2u(wd[1][1],px1,z1); z1=dot2u(wd[1][2],px2,z1);
        z1=dot2u(wd[1][3],d01,z1); z1=dot2u(wd[1][4],d23,z1); z1=dot2u(wd[1][5],d45,z1);
        z2=dot2u(wd[2][0],px0,z2); z2=dot2u(wd[2][1],px1,z2); z2=dot2u(wd[2][2],px2,z2);
        z2=dot2u(wd[2][3],d01,z2); z2=dot2u(wd[2][4],d23,z2); z2=dot2u(wd[2][5],d45,z2);
        z3=dot2u(wd[3][0],px0,z3); z3=dot2u(wd[3][1],px1,z3); z3=dot2u(wd[3][2],px2,z3);
        z3=dot2u(wd[3][3],d01,z3); z3=dot2u(wd[3][4],d23,z3); z3=dot2u(wd[3][5],d45,z3);
        const float iv = rcp_(1.0f + exp2_(z0));
        const float fv = rcp_(1.0f + exp2_(z1));
        const float gv = fmaf(2.0f, rcp_(1.0f + exp2_(z2)), -1.0f);
        const float ov = rcp_(1.0f + exp2_(z3));
        cc = fmaf(fv, cc, iv*gv);
        hn = ov * tanh_(cc);
        const float t0=swzbc<0>(hn), t1=swzbc<1>(hn), t2=swzbc<2>(hn),
                    t3=swzbc<3>(hn), t4=swzbc<4>(hn), t5=swzbc<5>(hn);
        d01=pkrtz(t0,t1); d23=pkrtz(t2,t3); d45=pkrtz(t4,t5);
    };

    f32x4 xA[3], xB[3];
    auto ldg = [&](int p, f32x4* d){
        const f32x4* q = (const f32x4*)(xb + (size_t)p*48);
        d[0]=q[0]; d[1]=q[1]; d[2]=q[2];
    };

    auto GROUP = [&](const f32x4* d, int p){
        u32 e0,e1,e2,o0,o1,o2;
        if (!dir){
            STEP(pkrtz(d[0].x,d[0].y), pkrtz(d[0].z,d[0].w), pkrtz(d[1].x,d[1].y));
            e0=d01; e1=d23; e2=d45;
            STEP(pkrtz(d[1].z,d[1].w), pkrtz(d[2].x,d[2].y), pkrtz(d[2].z,d[2].w));
            o0=d01; o1=d23; o2=d45;
        } else {
            STEP(pkrtz(d[1].z,d[1].w), pkrtz(d[2].x,d[2].y), pkrtz(d[2].z,d[2].w));
            o0=d01; o1=d23; o2=d45;
            STEP(pkrtz(d[0].x,d[0].y), pkrtz(d[0].z,d[0].w), pkrtz(d[1].x,d[1].y));
            e0=d01; e1=d23; e2=d45;
        }
        if (j < 3){
            const u32 se = (j==0)?e0:((j==1)?e1:e2);
            const u32 so = (j==0)?o0:((j==1)?o1:o2);
            u32x2 v; v.x=se; v.y=so;
            *(u32x2*)(obase + (size_t)p*tstr) = v;
        }
    };

    const int dp = dir ? -1 : 1;
    int p = dir ? (NT/2-1) : 0;
    {
        int p1 = p+dp; p1 = p1<0?0:(p1>NT/2-1?NT/2-1:p1);
        ldg(p, xA); ldg(p1, xB);
    }
    for (int it=0; it<NT/2; it+=2){
        GROUP(xA, p);
        { int pn=p+2*dp; pn = pn<0?0:(pn>NT/2-1?NT/2-1:pn); ldg(pn, xA); }
        p += dp;
        GROUP(xB, p);
        { int pn=p+2*dp; pn = pn<0?0:(pn>NT/2-1?NT/2-1:pn); ldg(pn, xB); }
        p += dp;
    }
}

// Layer 1 forward scan + r1 single step + FC head. 1024 blocks x 64.
__global__ __launch_bounds__(64)
__attribute__((amdgpu_waves_per_eu(1,1)))
void lstm_l1v2(
    const char* __restrict__ fbuf, const char* __restrict__ bbuf,
    const float* __restrict__ h0, const float* __restrict__ c0,
    const float* __restrict__ W1f, const float* __restrict__ U1f, const float* __restrict__ b1f,
    const float* __restrict__ W1b, const float* __restrict__ U1b, const float* __restrict__ b1b,
    const float* __restrict__ fcw, const float* __restrict__ fcb,
    float* __restrict__ out)
{
    const int l  = threadIdx.x;
    const int j  = l & 7;
    const int jj = (j < 6) ? j : (j - 2);
    const int b  = blockIdx.x*8 + (l >> 3);

    // wd1[g][k]: k=0..2 -> W1f cols 0-5 (f0 pairs); k=3..5 -> W1f cols 6-11 (r0);
    // k=6..8 -> U1f cols 0-5 (h1 pairs)
    u32 wd1[4][9]; float cEb[4];
#pragma unroll
    for (int g=0; g<4; ++g){
        const int row = g*6 + jj;
        const float cs = (g==2) ? -2.88539008177792681f : -1.44269504088896341f;
#pragma unroll
        for (int k=0;k<3;++k) wd1[g][k]   = pkrtz(cs*W1f[row*12+2*k],   cs*W1f[row*12+2*k+1]);
#pragma unroll
        for (int k=0;k<3;++k) wd1[g][3+k] = pkrtz(cs*W1f[row*12+6+2*k], cs*W1f[row*12+6+2*k+1]);
#pragma unroll
        for (int k=0;k<3;++k) wd1[g][6+k] = pkrtz(cs*U1f[row*6+2*k],    cs*U1f[row*6+2*k+1]);
        cEb[g] = cs * b1f[row];
    }
#pragma unroll
    for (int g=0; g<4; ++g){
#pragma unroll
        for (int k=0;k<9;++k) PINF(wd1[g][k]);
        PINF(cEb[g]);
    }

    float cc = c0[2*(NB*6) + b*6 + jj];
    float hn = h0[2*(NB*6) + b*6 + jj];
    u32 d01, d23, d45;
    {
        const float t0=swzbc<0>(hn), t1=swzbc<1>(hn), t2=swzbc<2>(hn),
                    t3=swzbc<3>(hn), t4=swzbc<4>(hn), t5=swzbc<5>(hn);
        d01=pkrtz(t0,t1); d23=pkrtz(t2,t3); d45=pkrtz(t4,t5);
    }

    const char* fp = fbuf + (size_t)b*24;
    const char* rp = bbuf + (size_t)b*24;
    const size_t tstr = (size_t)NB*24;

    auto STEP = [&](u32 f0d, u32 f1d, u32 f2d, u32 r0d, u32 r1d, u32 r2d){
        float z0=cEb[0], z1=cEb[1], z2=cEb[2], z3=cEb[3];
        z0=dot2u(wd1[0][0],f0d,z0); z0=dot2u(wd1[0][1],f1d,z0); z0=dot2u(wd1[0][2],f2d,z0);
        z0=dot2u(wd1[0][3],r0d,z0); z0=dot2u(wd1[0][4],r1d,z0); z0=dot2u(wd1[0][5],r2d,z0);
        z0=dot2u(wd1[0][6],d01,z0); z0=dot2u(wd1[0][7],d23,z0); z0=dot2u(wd1[0][8],d45,z0);
        z1=dot2u(wd1[1][0],f0d,z1); z1=dot2u(wd1[1][1],f1d,z1); z1=dot2u(wd1[1][2],f2d,z1);
        z1=dot2u(wd1[1][3],r0d,z1); z1=dot2u(wd1[1][4],r1d,z1); z1=dot2u(wd1[1][5],r2d,z1);
        z1=dot2u(wd1[1][6],d01,z1); z1=dot2u(wd1[1][7],d23,z1); z1=dot2u(wd1[1][8],d45,z1);
        z2=dot2u(wd1[2][0],f0d,z2); z2=dot2u(wd1[2][1],f1d,z2); z2=dot2u(wd1[2][2],f2d,z2);
        z2=dot2u(wd1[2][3],r0d,z2); z2=dot2u(wd1[2][4],r1d,z2); z2=dot2u(wd1[2][5],r2d,z2);
        z2=dot2u(wd1[2][6],d01,z2); z2=dot2u(wd1[2][7],d23,z2); z2=dot2u(wd1[2][8],d45,z2);
        z3=dot2u(wd1[3][0],f0d,z3); z3=dot2u(wd1[3][1],f1d,z3); z3=dot2u(wd1[3][2],f2d,z3);
        z3=dot2u(wd1[3][3],r0d,z3); z3=dot2u(wd1[3][4],r1d,z3); z3=dot2u(wd1[3][5],r2d,z3);
        z3=dot2u(wd1[3][6],d01,z3); z3=dot2u(wd1[3][7],d23,z3); z3=dot2u(wd1[3][8],d45,z3);
        const float iv = rcp_(1.0f + exp2_(z0));
        const float fv = rcp_(1.0f + exp2_(z1));
        const float gv = fmaf(2.0f, rcp_(1.0f + exp2_(z2)), -1.0f);
        const float ov = rcp_(1.0f + exp2_(z3));
        cc = fmaf(fv, cc, iv*gv);
        hn = ov * tanh_(cc);
        const float t0=swzbc<0>(hn), t1=swzbc<1>(hn), t2=swzbc<2>(hn),
                    t3=swzbc<3>(hn), t4=swzbc<4>(hn), t5=swzbc<5>(hn);
        d01=pkrtz(t0,t1); d23=pkrtz(t2,t3); d45=pkrtz(t4,t5);
    };

    u32x2 FA[3], RA[3], FB[3], RB[3];
    auto ldp = [&](int p, u32x2* F, u32x2* R){
        const u32x2* f = (const u32x2*)(fp + (size_t)p*tstr);
        const u32x2* r = (const u32x2*)(rp + (size_t)p*tstr);
        F[0]=f[0]; F[1]=f[1]; F[2]=f[2];
        R[0]=r[0]; R[1]=r[1]; R[2]=r[2];
    };
    auto GROUP = [&](const u32x2* F, const u32x2* R){
        STEP(F[0].x, F[1].x, F[2].x, R[0].x, R[1].x, R[2].x);
        STEP(F[0].y, F[1].y, F[2].y, R[0].y, R[1].y, R[2].y);
    };

    ldp(0, FA, RA); ldp(1, FB, RB);
    for (int p=0; p<NT/2; p+=2){
        GROUP(FA, RA);
        { int pn=p+2; pn = pn>NT/2-1?NT/2-1:pn; ldp(pn, FA, RA); }
        GROUP(FB, RB);
        { int pn=p+3; pn = pn>NT/2-1?NT/2-1:pn; ldp(pn, FB, RB); }
    }
    // hn = h1[511] (f32, lane j = hidden j)

    // ---- l0[511] as f32 (odd dwords of pair 255) ----
    float v[12];
    {
        const char* f255 = fp + (size_t)(NT/2-1)*tstr;
        const char* r255 = rp + (size_t)(NT/2-1)*tstr;
#pragma unroll
        for (int k=0;k<3;++k){
            const u32 fd = *(const u32*)(f255 + k*8 + 4);
            const u32 rd = *(const u32*)(r255 + k*8 + 4);
            v[2*k]   = upk_lo(fd);  v[2*k+1]   = upk_hi(fd);
            v[6+2*k] = upk_lo(rd);  v[6+2*k+1] = upk_hi(rd);
        }
    }

    // ---- r1: single reverse-direction step at t = NT-1 (f32 math) ----
    const int base3 = 3*(NB*6) + b*6;
    float hr6[6];
#pragma unroll
    for (int k=0;k<6;++k) hr6[k] = h0[base3 + k];
    float cr = c0[base3 + jj];

    float zr[4];
#pragma unroll
    for (int g=0; g<4; ++g){
        const int row = g*6 + jj;
        float acc = b1b[row];
#pragma unroll
        for (int k=0;k<12;++k) acc = fmaf(W1b[row*12+k], v[k], acc);
#pragma unroll
        for (int k=0;k<6;++k)  acc = fmaf(U1b[row*6+k], hr6[k], acc);
        zr[g] = acc;
    }
    {
        const float iv = sigm(zr[0]);
        const float fv = sigm(zr[1]);
        const float gv = tanh_(zr[2]);
        cr = fmaf(fv, cr, iv*gv);
    }
    const float hrv = sigm(zr[3]) * tanh_(cr);

    // ---- head: out[b][j] = fcb[j] + fcw[j] . relu([h1; r1]) ----
    float u[12];
    u[0]=fmaxf(swzbc<0>(hn),0.f); u[1]=fmaxf(swzbc<1>(hn),0.f); u[2]=fmaxf(swzbc<2>(hn),0.f);
    u[3]=fmaxf(swzbc<3>(hn),0.f); u[4]=fmaxf(swzbc<4>(hn),0.f); u[5]=fmaxf(swzbc<5>(hn),0.f);
    u[6]=fmaxf(swzbc<0>(hrv),0.f); u[7]=fmaxf(swzbc<1>(hrv),0.f); u[8]=fmaxf(swzbc<2>(hrv),0.f);
    u[9]=fmaxf(swzbc<3>(hrv),0.f); u[10]=fmaxf(swzbc<4>(hrv),0.f); u[11]=fmaxf(swzbc<5>(hrv),0.f);
    if (j < 6){
        float acc = fcb[j];
#pragma unroll
        for (int k=0;k<12;++k) acc = fmaf(fcw[j*12+k], u[k], acc);
        out[b*6 + j] = acc;
    }
}

extern "C" void kernel_launch(void* const* d_in, const int* in_sizes, int n_in,
                              void* d_out, int out_size, void* d_ws, size_t ws_size,
                              hipStream_t stream)
{
    (void)in_sizes; (void)n_in; (void)out_size; (void)ws_size;
    const float* x    = (const float*)d_in[0];
    const float* h0   = (const float*)d_in[1];
    const float* c0   = (const float*)d_in[2];
    const float* W0f  = (const float*)d_in[3];
    const float* U0f  = (const float*)d_in[4];
    const float* b0f  = (const float*)d_in[5];
    const float* W0b  = (const float*)d_in[6];
    const float* U0b  = (const float*)d_in[7];
    const float* b0b  = (const float*)d_in[8];
    const float* W1f  = (const float*)d_in[9];
    const float* U1f  = (const float*)d_in[10];
    const float* b1f  = (const float*)d_in[11];
    const float* W1b  = (const float*)d_in[12];
    const float* U1b  = (const float*)d_in[13];
    const float* b1b  = (const float*)d_in[14];
    const float* fcw  = (const float*)d_in[15];
    const float* fcb  = (const float*)d_in[16];
    float* out = (float*)d_out;
    char* ws = (char*)d_ws;

    char* fbuf = ws;
    char* bbuf = ws + (size_t)(NT/2)*NB*24;   // 2 x 50.3 MB

    lstm_l0v2<<<dim3(2048), dim3(64), 0, stream>>>(x, h0, c0, W0f, U0f, b0f, W0b, U0b, b0b, fbuf, bbuf);
    lstm_l1v2<<<dim3(1024), dim3(64), 0, stream>>>(fbuf, bbuf, h0, c0,
        W1f, U1f, b1f, W1b, U1b, b1b, fcw, fcb, out);
}